// Round 6
// baseline (296.645 us; speedup 1.0000x reference)
//
#include <hip/hip_runtime.h>
#include <math.h>

#define Hh 96
#define Ww 96
#define NPIX 9216
#define RAD 15
#define TAPS 31
#define NCH 144            // chunks of 64 sorted pixels (= j-wave groups)
#define NSB 16             // i-split factor for bilateral partials
#define NBIN 4096
#define EPSV 1e-20f
#define LOG2E 1.4426950408889634f
#define CUT2 60.0f         // boxdist_h^2 > 60  =>  k < 2^-30  => safe to skip

// ---- ws layout (float-unit offsets) — total ~280k floats = 1.12 MB ----
#define OFF_F    0                       // 8*NPIX  feat_sorted: h0..h4, a, q, pad
#define OFF_Q    (8*NPIX)                // NPIX    q in ORIGINAL pixel order
#define OFF_CBI  (9*NPIX)                // NPIX    bilateral colsum, SORTED order
#define OFF_ROWW (10*NPIX)               // 96
#define OFF_WTAB (10*NPIX+96)            // 31 (padded to 256)
#define OFF_BBOX (10*NPIX+256)           // NCH*12  (min[5], max[5], pad2)
#define OFF_PB   (10*NPIX+256+NCH*12)    // NSB*NPIX partials, SORTED order
// int-typed regions (same 4-byte units):
#define OFF_HIST (OFF_PB + NSB*NPIX)     // 4096
#define OFF_BASE (OFF_HIST + NBIN)       // 4096
#define OFF_INV  (OFF_BASE + NBIN)       // NPIX   original n -> sorted pos
#define OFF_CNT  (OFF_INV + NPIX)        // NCH
#define OFF_LIST (OFF_CNT + NCH)         // NCH*NCH survivor chunk ids

__device__ __forceinline__ int color_key(float r, float g, float b){
  int rq = min(15, (int)r >> 4);
  int gq = min(15, (int)g >> 4);
  int bq = min(15, (int)b >> 4);
  int key = 0;
  #pragma unroll
  for (int k=0;k<4;k++){
    key |= ((rq>>k)&1) << (3*k+2);
    key |= ((gq>>k)&1) << (3*k+1);
    key |= ((bq>>k)&1) << (3*k);
  }
  return key;
}

// zero histogram + spatial tables
__global__ __launch_bounds__(256) void init_kernel(float* __restrict__ ws){
  int t = threadIdx.x;
  int* hist = (int*)ws + OFF_HIST;
  for (int i=t;i<NBIN;i+=256) hist[i]=0;
  if (t < Hh){
    float s = 0.f;
    for (int yy=0; yy<Hh; ++yy){
      float d = (float)(yy - t);
      s += expf(-d*d*(1.0f/18.0f));
    }
    ws[OFF_ROWW + t] = s;
  }
  if (t >= 128 && t < 128 + TAPS){
    int d = (t - 128) - RAD;
    ws[OFF_WTAB + (t-128)] = expf(-(float)(d*d)*(1.0f/18.0f));
  }
}

__global__ __launch_bounds__(256) void hist_kernel(const float* __restrict__ image,
                                                   float* __restrict__ ws){
  int n = blockIdx.x*256 + threadIdx.x;
  int key = color_key(image[n], image[NPIX+n], image[2*NPIX+n]);
  atomicAdd((int*)ws + OFF_HIST + key, 1);
}

// exclusive prefix sum over 4096 bins, one block of 256
__global__ __launch_bounds__(256) void scan_kernel(float* __restrict__ ws){
  __shared__ int part[256];
  const int* hist = (const int*)ws + OFF_HIST;
  int* base = (int*)ws + OFF_BASE;
  int t = threadIdx.x;
  int loc[16]; int s = 0;
  #pragma unroll
  for (int i=0;i<16;i++){ loc[i] = s; s += hist[t*16+i]; }
  part[t] = s; __syncthreads();
  for (int off=1; off<256; off<<=1){
    int v = (t>=off) ? part[t-off] : 0;
    __syncthreads();
    part[t] += v;
    __syncthreads();
  }
  int b = (t==0) ? 0 : part[t-1];
  #pragma unroll
  for (int i=0;i<16;i++) base[t*16+i] = b + loc[i];
}

// scatter: sorted position + build feat_sorted
__global__ __launch_bounds__(256) void scatter_kernel(const float* __restrict__ image,
                                                      float* __restrict__ ws){
  int n = blockIdx.x*256 + threadIdx.x;
  float r = image[n], g = image[NPIX+n], b = image[2*NPIX+n];
  int key = color_key(r,g,b);
  int pos = atomicAdd((int*)ws + OFF_BASE + key, 1);
  ((int*)ws)[OFF_INV + n] = pos;
  int y = n / Ww, x = n % Ww;
  const float c  = 0.7213475205f;   // 0.5/ln2
  const float sc = 1.2011224088f;   // sqrt(2c)
  float f0 = (float)y * (1.0f/160.0f);
  float f1 = (float)x * (1.0f/160.0f);
  float f2 = r * (1.0f/3.0f);
  float f3 = g * (1.0f/3.0f);
  float f4 = b * (1.0f/3.0f);
  float a = c*(f0*f0+f1*f1+f2*f2+f3*f3+f4*f4);
  float* F = ws + OFF_F + (size_t)pos*8;
  F[0]=sc*f0; F[1]=sc*f1; F[2]=sc*f2; F[3]=sc*f3; F[4]=sc*f4;
  F[5]=a; F[6]=0.f; F[7]=0.f;
}

// per-chunk 5-D bbox of h-features (one wave per chunk)
__global__ __launch_bounds__(256) void bbox_kernel(float* __restrict__ ws){
  int wid = threadIdx.x >> 6, lane = threadIdx.x & 63;
  int ch = blockIdx.x*4 + wid;
  const float* F = ws + OFF_F + ((size_t)ch*64 + lane)*8;
  float4 A = *(const float4*)F;
  float4 B = *(const float4*)(F+4);
  float mn[5] = {A.x,A.y,A.z,A.w,B.x};
  float mx[5] = {A.x,A.y,A.z,A.w,B.x};
  #pragma unroll
  for (int m=32; m; m>>=1){
    #pragma unroll
    for (int d=0;d<5;d++){
      mn[d] = fminf(mn[d], __shfl_xor(mn[d], m));
      mx[d] = fmaxf(mx[d], __shfl_xor(mx[d], m));
    }
  }
  if (lane == 0){
    float* bb = ws + OFF_BBOX + ch*12;
    #pragma unroll
    for (int d=0;d<5;d++){ bb[d]=mn[d]; bb[5+d]=mx[d]; }
  }
}

// survivor lists: for each j-group, chunks with boxdist^2 <= CUT2
__global__ __launch_bounds__(256) void cull_kernel(float* __restrict__ ws){
  int wid = threadIdx.x >> 6, lane = threadIdx.x & 63;
  int jg = blockIdx.x*4 + wid;
  const float* wb = ws + OFF_BBOX + jg*12;
  float wmn[5], wmx[5];
  #pragma unroll
  for (int d=0;d<5;d++){ wmn[d]=wb[d]; wmx[d]=wb[5+d]; }
  int* cnt  = (int*)ws + OFF_CNT;
  int* list = (int*)ws + OFF_LIST + jg*NCH;
  int base = 0;
  #pragma unroll
  for (int r=0;r<3;r++){
    int c = lane + 64*r;
    bool sv = false;
    if (c < NCH){
      const float* cb = ws + OFF_BBOX + c*12;
      float s = 0.f;
      #pragma unroll
      for (int d=0;d<5;d++){
        float gap = fmaxf(0.f, fmaxf(cb[d]-wmx[d], wmn[d]-cb[5+d]));
        s = fmaf(gap, gap, s);
      }
      sv = (s <= CUT2);
    }
    unsigned long long m = __ballot(sv);
    if (sv){
      int pos = __popcll(m & ((1ull<<lane)-1ull));
      list[base+pos] = c;
    }
    base += __popcll(m);
  }
  if (lane == 0) cnt[jg] = base;
}

// COLSUM=1: sum_i k_ij;  COLSUM=0: sum_i q_i k_ij.  Sorted-j indexing.
template<int COLSUM>
__global__ __launch_bounds__(256) void bilateral_kernel(float* __restrict__ ws){
  int wid = threadIdx.x >> 6, lane = threadIdx.x & 63;
  int jb = blockIdx.x % 36, s = blockIdx.x / 36;
  int jg = jb*4 + wid;
  int js = jg*64 + lane;
  const float* F = ws + OFF_F;
  float4 A = *(const float4*)(F + (size_t)js*8);
  float4 B = *(const float4*)(F + (size_t)js*8 + 4);
  float h0=A.x, h1=A.y, h2=A.z, h3=A.w, h4=B.x, na=-B.y;
  const int* cnt  = (const int*)ws + OFF_CNT;
  const int* list = (const int*)ws + OFF_LIST + jg*NCH;
  int n = cnt[jg];
  float acc = 0.f;
  for (int t=s; t<n; t+=NSB){
    int c = list[t];
    const float* fi = F + (size_t)c*512;
    #pragma unroll 4
    for (int ii=0; ii<64; ii++){
      float4 w0 = *(const float4*)(fi + ii*8);
      float4 w1 = *(const float4*)(fi + ii*8 + 4);
      float e = na - w1.y;
      e = fmaf(h0, w0.x, e);
      e = fmaf(h1, w0.y, e);
      e = fmaf(h2, w0.z, e);
      e = fmaf(h3, w0.w, e);
      e = fmaf(h4, w1.x, e);
      float kk = __builtin_amdgcn_exp2f(e);
      if (COLSUM) acc += kk;
      else        acc = fmaf(kk, w1.z, acc);
    }
  }
  ws[OFF_PB + (size_t)s*NPIX + js] = acc;
}

// reduce colsum partials -> CBI (sorted), initial softmax q
__global__ __launch_bounds__(256) void prep0_kernel(const float* __restrict__ logits,
                                                    float* __restrict__ ws){
  int n = blockIdx.x*256 + threadIdx.x;
  const float* pB = ws + OFF_PB;
  float cb = 0.f;
  #pragma unroll
  for (int s=0;s<NSB;s++) cb += pB[(size_t)s*NPIX + n];
  ws[OFF_CBI + n] = cb;
  float c0 = logits[n], c1 = logits[NPIX+n];
  float q = 1.0f / (1.0f + __builtin_amdgcn_exp2f((c1-c0)*LOG2E));
  ws[OFF_Q + n] = q;
  int pos = ((const int*)ws)[OFF_INV + n];
  ws[OFF_F + (size_t)pos*8 + 6] = q;
}

__global__ __launch_bounds__(256) void combine_kernel(const float* __restrict__ logits,
                                                      const float* __restrict__ Wsp,
                                                      const float* __restrict__ Wbi,
                                                      const float* __restrict__ Cm,
                                                      float* __restrict__ ws,
                                                      float* __restrict__ out){
  __shared__ float tq[46][48];
  __shared__ float tr[46][17];
  __shared__ float wt[TAPS];
  int tx = threadIdx.x & 15, ty = threadIdx.x >> 4;
  int bx = blockIdx.x % 6, by = blockIdx.x / 6;
  int x0 = bx*16, y0 = by*16;

  const float* q0g = ws + OFF_Q;
  for (int idx = threadIdx.x; idx < 46*46; idx += 256){
    int ly = idx / 46, lx = idx % 46;
    int gy = y0 - RAD + ly, gx = x0 - RAD + lx;
    float v = 0.f;
    if (gy >= 0 && gy < Hh && gx >= 0 && gx < Ww) v = q0g[gy*Ww + gx];
    tq[ly][lx] = v;
  }
  if (threadIdx.x < TAPS) wt[threadIdx.x] = ws[OFF_WTAB + threadIdx.x];
  __syncthreads();

  // separable spatial filter: rows then columns
  for (int idx = threadIdx.x; idx < 46*16; idx += 256){
    int ly = idx >> 4, lx = idx & 15;
    float in = 0.f;
    #pragma unroll
    for (int dx=0; dx<TAPS; dx++) in = fmaf(wt[dx], tq[ly][lx+dx], in);
    tr[ly][lx] = in;
  }
  __syncthreads();

  int y = y0 + ty, x = x0 + tx, j = y*Ww + x;
  float S = 0.f;
  #pragma unroll
  for (int dy=0; dy<TAPS; dy++) S = fmaf(wt[dy], tr[ty+dy][tx], S);

  int js = ((const int*)ws)[OFF_INV + j];
  const float* pB = ws + OFF_PB;
  float Bv = 0.f;
  #pragma unroll
  for (int s=0;s<NSB;s++) Bv += pB[(size_t)s*NPIX + js];

  float Cb  = ws[OFF_CBI + js];
  float nb  = 1.0f/(Cb + EPSV);
  float Csp = ws[OFF_ROWW + y] * ws[OFF_ROWW + x];
  float nsp = 1.0f/(Csp + EPSV);

  float sp0 = S*nsp,  sp1 = (Csp - S)*nsp;    // q1 = 1 - q0 identity
  float bi0 = Bv*nb,  bi1 = (Cb - Bv)*nb;

  float m0 = Wsp[0]*sp0 + Wsp[1]*sp1 + Wbi[0]*bi0 + Wbi[1]*bi1;
  float m1 = Wsp[2]*sp0 + Wsp[3]*sp1 + Wbi[2]*bi0 + Wbi[3]*bi1;
  float cm0 = Cm[0]*m0 + Cm[1]*m1;
  float cm1 = Cm[2]*m0 + Cm[3]*m1;

  float o0 = logits[j]        - cm0;
  float o1 = logits[NPIX + j] - cm1;
  out[j]        = o0;
  out[NPIX + j] = o1;

  // fused softmax for next iteration (extra write on last iter harmless)
  float q = 1.0f / (1.0f + __builtin_amdgcn_exp2f((o1-o0)*LOG2E));
  ws[OFF_Q + j] = q;
  ws[OFF_F + (size_t)js*8 + 6] = q;
}

extern "C" void kernel_launch(void* const* d_in, const int* in_sizes, int n_in,
                              void* d_out, int out_size, void* d_ws, size_t ws_size,
                              hipStream_t stream){
  const float* image  = (const float*)d_in[0];
  const float* logits = (const float*)d_in[1];
  const float* Wsp    = (const float*)d_in[2];
  const float* Wbi    = (const float*)d_in[3];
  const float* Cm     = (const float*)d_in[4];
  float* out = (float*)d_out;
  float* ws  = (float*)d_ws;

  init_kernel   <<<1, 256, 0, stream>>>(ws);
  hist_kernel   <<<36, 256, 0, stream>>>(image, ws);
  scan_kernel   <<<1, 256, 0, stream>>>(ws);
  scatter_kernel<<<36, 256, 0, stream>>>(image, ws);
  bbox_kernel   <<<36, 256, 0, stream>>>(ws);
  cull_kernel   <<<36, 256, 0, stream>>>(ws);

  bilateral_kernel<1><<<NSB*36, 256, 0, stream>>>(ws);   // colsum (iteration-invariant)
  prep0_kernel  <<<36, 256, 0, stream>>>(logits, ws);

  for (int t=0; t<5; ++t){
    bilateral_kernel<0><<<NSB*36, 256, 0, stream>>>(ws);
    combine_kernel<<<36, 256, 0, stream>>>(logits, Wsp, Wbi, Cm, ws, out);
  }
}